// Round 1
// baseline (134.011 us; speedup 1.0000x reference)
//
#include <hip/hip_runtime.h>

// DWT db4, 3 levels, symmetric extension, + linear resize to T=2048, stack 4 coeffs.
// x: [B=16, T=2048, N=512, 1] f32   -> out: [B, N, T, 4] f32
// row = b*N + n (8192 rows). Lengths: a0=2048 -> (cA1,cD1)=1027 -> (cA2,cD2)=517 -> (cA3,cD3)=262
// out[..., 0]=cA3, 1=cD3, 2=cD2, 3=cD1 (each resized to 2048).

#define TPB   256
#define ROWS  4
#define TLEN  2048
#define NCH   512
// per-row LDS region layout (floats):
//   [0 .. 2048)    : a0            (dead after L1)  -> cA2@0(517), cD2@517(517), cA3@1034(262), cD3@1296(262)
//   [2048 .. 3075) : cA1 (1027)    (dead after L2)
//   [3075 .. 4102) : cD1 (1027)    (live until resize)
#define RSTRIDE 4102
#define CA1_OFF 2048
#define CD1_OFF 3075
#define CA2_OFF 0
#define CD2_OFF 517
#define CA3_OFF 1034
#define CD3_OFF 1296

__device__ __forceinline__ int sym_idx(int e, int S) {
    // ext index e in [0, S+12] of symmetric_pad(a, 7,7)[1:] -> source index into a[0..S)
    int m = e - 6;
    m = (m < 0) ? (-1 - m) : m;          // left reflection (drop-first accounted)
    m = (m >= S) ? (2 * S - 1 - m) : m;  // right reflection
    return m;
}

__device__ __forceinline__ void dwt_level(float* lds, int in_off, int S,
                                          int lo_off, int hi_off, int O, int tid) {
    const float LO[8] = {-0.010597401784997278f,  0.032883011666982945f,  0.030841381835986965f,
                         -0.18703481171888114f,  -0.02798376941698385f,   0.6308807679295904f,
                          0.7148465705525415f,    0.23037781330885523f};
    const float HI[8] = {-0.23037781330885523f,   0.7148465705525415f,   -0.6308807679295904f,
                         -0.02798376941698385f,   0.18703481171888114f,   0.030841381835986965f,
                         -0.032883011666982945f, -0.010597401784997278f};
    for (int i = tid; i < ROWS * O; i += TPB) {
        const int r = i & 3;
        const int j = i >> 2;
        float* rowp = lds + r * RSTRIDE;
        const float* in = rowp + in_off;
        float slo = 0.0f, shi = 0.0f;
        const int e0 = 2 * j + 7;
        #pragma unroll
        for (int k = 0; k < 8; ++k) {
            const float v = in[sym_idx(e0 - k, S)];
            slo = fmaf(LO[k], v, slo);
            shi = fmaf(HI[k], v, shi);
        }
        rowp[lo_off + j] = slo;
        rowp[hi_off + j] = shi;
    }
}

__device__ __forceinline__ float lerp_read(const float* c, int S, int t) {
    // torch F.interpolate linear align_corners=False, matching the reference op order
    const float scale = (float)S * (1.0f / 2048.0f);   // exact in fp32 for S in {262,517,1027}
    float p = ((float)t + 0.5f) * scale - 0.5f;
    p = fminf(fmaxf(p, 0.0f), (float)(S - 1));
    const int i0 = (int)p;                 // p >= 0 -> trunc == floor
    const int i1 = min(i0 + 1, S - 1);
    const float w = p - (float)i0;
    return c[i0] * (1.0f - w) + c[i1] * w;
}

__global__ __launch_bounds__(TPB)
void dwt_kernel(const float* __restrict__ x, float* __restrict__ out) {
    __shared__ float lds[ROWS * RSTRIDE];   // 65,632 B
    const int tid  = threadIdx.x;
    const int row0 = blockIdx.x * ROWS;     // rows row0..row0+3, same b (4 | 512)
    const int b    = row0 >> 9;             // / 512
    const int n0   = row0 & 511;

    // ---- load: x[b, t, n0..n0+3] -> lds rows (one float4 per (lane,t)) ----
    const float4* src = (const float4*)(x + (size_t)b * TLEN * NCH + n0);
    #pragma unroll
    for (int t = tid; t < TLEN; t += TPB) {
        const float4 v = src[t * (NCH / 4)];
        lds[0 * RSTRIDE + t] = v.x;
        lds[1 * RSTRIDE + t] = v.y;
        lds[2 * RSTRIDE + t] = v.z;
        lds[3 * RSTRIDE + t] = v.w;
    }
    __syncthreads();

    // ---- level 1: a0(2048) -> cA1, cD1 (1027) ----
    dwt_level(lds, 0, 2048, CA1_OFF, CD1_OFF, 1027, tid);
    __syncthreads();

    // ---- level 2: cA1(1027) -> cA2, cD2 (517), reusing a0's region ----
    dwt_level(lds, CA1_OFF, 1027, CA2_OFF, CD2_OFF, 517, tid);
    __syncthreads();

    // ---- level 3: cA2(517) -> cA3, cD3 (262) ----
    dwt_level(lds, CA2_OFF, 517, CA3_OFF, CD3_OFF, 262, tid);
    __syncthreads();

    // ---- resize each coeff to 2048 and write [row, t, 4] as float4 ----
    float4* dst = (float4*)out + (size_t)row0 * TLEN;
    for (int i = tid; i < ROWS * TLEN; i += TPB) {
        const int r = i >> 11;          // / 2048
        const int t = i & (TLEN - 1);
        const float* rowp = lds + r * RSTRIDE;
        float4 o;
        o.x = lerp_read(rowp + CA3_OFF, 262, t);
        o.y = lerp_read(rowp + CD3_OFF, 262, t);
        o.z = lerp_read(rowp + CD2_OFF, 517, t);
        o.w = lerp_read(rowp + CD1_OFF, 1027, t);
        dst[i] = o;                     // (row0+r)*2048 + t == row0*2048 + i
    }
}

extern "C" void kernel_launch(void* const* d_in, const int* in_sizes, int n_in,
                              void* d_out, int out_size, void* d_ws, size_t ws_size,
                              hipStream_t stream) {
    const float* x = (const float*)d_in[0];
    float* out = (float*)d_out;
    const int n_rows = 16 * 512;                    // B*N
    dim3 grid(n_rows / ROWS), block(TPB);
    hipLaunchKernelGGL(dwt_kernel, grid, block, 0, stream, x, out);
}

// Round 3
// 60.934 us; speedup vs baseline: 2.1993x; 2.1993x over previous
//
#include <hip/hip_runtime.h>

// DWT db4, 3 levels, symmetric extension, + linear resize to T=2048, stack 4 coeffs.
// x: [B=16, T=2048, N=512, 1] f32   -> out: [B, N, T, 4] f32
// Lengths: a0=2048 -> (cA1,cD1)=1027 -> (cA2,cD2)=517 -> (cA3,cD3)=262
// out[..., 0]=cA3, 1=cD3, 2=cD2, 3=cD1 (each linearly resized to 2048).

#define TPB   512
#define ROWS  4
#define TLEN  2048
#define NCH   512
// per-row LDS layout (floats), RSTRIDE=4104 (8B-aligned rows, <=2-way bank aliasing):
//   [0 .. 2048)    : a0 (dead after L1) -> cA2@0(517), cD2@517(517), cA3@1034(262), cD3@1296(262)
//   [2048 .. 3075) : cA1 (1027, dead after L2)
//   [3075 .. 4102) : cD1 (1027, live until resize)
#define RSTRIDE 4104
#define CA1_OFF 2048
#define CD1_OFF 3075
#define CA2_OFF 0
#define CD2_OFF 517
#define CA3_OFF 1034
#define CD3_OFF 1296

typedef float f32x4 __attribute__((ext_vector_type(4)));

// forward filters (for boundary/sym path)
__constant__ float LO[8] = {-0.010597401784997278f,  0.032883011666982945f,  0.030841381835986965f,
                            -0.18703481171888114f,  -0.02798376941698385f,   0.6308807679295904f,
                             0.7148465705525415f,    0.23037781330885523f};
__constant__ float HI[8] = {-0.23037781330885523f,   0.7148465705525415f,   -0.6308807679295904f,
                            -0.02798376941698385f,   0.18703481171888114f,   0.030841381835986965f,
                            -0.032883011666982945f, -0.010597401784997278f};
// reversed filters (interior path reads in[2j-6 .. 2j+1] ascending)
__constant__ float RLO[8] = { 0.23037781330885523f,   0.7148465705525415f,   0.6308807679295904f,
                             -0.02798376941698385f,  -0.18703481171888114f,  0.030841381835986965f,
                              0.032883011666982945f, -0.010597401784997278f};
__constant__ float RHI[8] = {-0.010597401784997278f, -0.032883011666982945f, 0.030841381835986965f,
                              0.18703481171888114f,  -0.02798376941698385f,  -0.6308807679295904f,
                              0.7148465705525415f,   -0.23037781330885523f};

__device__ __forceinline__ int sym_idx(int e, int S) {
    int m = e - 6;
    m = (m < 0) ? (-1 - m) : m;
    m = (m >= S) ? (2 * S - 1 - m) : m;
    return m;
}

__device__ __forceinline__ void dwt_level(float* lds, int in_off, int S,
                                          int lo_off, int hi_off, int tid) {
    const int O    = (S + 7) >> 1;      // output length
    const int jmax = (S - 2) >> 1;      // last interior j
    const int NI   = jmax - 2;          // interior count (j in [3, jmax])
    const int NB   = O - NI;            // boundary count (3 low + rest high)

    // interior: 8 contiguous input floats, 4x ds_read_b64, no branches
    for (int i = tid; i < ROWS * NI; i += TPB) {
        const int r = i & 3;
        const int j = (i >> 2) + 3;
        float* rowp = lds + r * RSTRIDE;
        const float* p = rowp + in_off + 2 * j - 6;   // 8B-aligned
        float v[8];
        *(float2*)&v[0] = ((const float2*)p)[0];
        *(float2*)&v[2] = ((const float2*)p)[1];
        *(float2*)&v[4] = ((const float2*)p)[2];
        *(float2*)&v[6] = ((const float2*)p)[3];
        float slo = 0.0f, shi = 0.0f;
        #pragma unroll
        for (int k = 0; k < 8; ++k) {
            slo = fmaf(RLO[k], v[k], slo);
            shi = fmaf(RHI[k], v[k], shi);
        }
        rowp[lo_off + j] = slo;
        rowp[hi_off + j] = shi;
    }
    // boundary: symmetric extension, only NB (6-7) outputs per row
    for (int i = tid; i < ROWS * NB; i += TPB) {
        const int r  = i & 3;
        const int bj = i >> 2;
        const int j  = (bj < 3) ? bj : (jmax + bj - 2);
        float* rowp = lds + r * RSTRIDE;
        const float* in = rowp + in_off;
        float slo = 0.0f, shi = 0.0f;
        const int e0 = 2 * j + 7;
        #pragma unroll
        for (int k = 0; k < 8; ++k) {
            const float v = in[sym_idx(e0 - k, S)];
            slo = fmaf(LO[k], v, slo);
            shi = fmaf(HI[k], v, shi);
        }
        rowp[lo_off + j] = slo;
        rowp[hi_off + j] = shi;
    }
}

__device__ __forceinline__ void lerp_coef(int S, int t, int& i0, int& i1, float& w) {
    // torch F.interpolate linear align_corners=False
    const float scale = (float)S * (1.0f / 2048.0f);   // exact fp32 for S in {262,517,1027}
    float p = ((float)t + 0.5f) * scale - 0.5f;
    p = fminf(fmaxf(p, 0.0f), (float)(S - 1));
    i0 = (int)p;
    i1 = min(i0 + 1, S - 1);
    w = p - (float)i0;
}

__device__ __forceinline__ float mix2(float a, float b, float w) {
    return a * (1.0f - w) + b * w;
}

__global__ __launch_bounds__(TPB)
void dwt_kernel(const float* __restrict__ x, float* __restrict__ out) {
    __shared__ float lds[ROWS * RSTRIDE];   // 65,664 B -> 2 blocks/CU, 16 waves/CU
    const int tid = threadIdx.x;

    // chunked XCD swizzle: physical bid p -> XCD p%8; give each XCD a
    // contiguous chunk of logical blocks so line-sharing blocks co-reside.
    const int nwg   = gridDim.x;            // 2048, divisible by 8
    const int chunk = nwg >> 3;
    const int p     = blockIdx.x;
    const int bid   = (p & 7) * chunk + (p >> 3);

    const int row0 = bid * ROWS;            // 4 consecutive n, same b
    const int b    = row0 >> 9;
    const int n0   = row0 & 511;

    // ---- load: x[b, t, n0..n0+3] -> 4 LDS rows ----
    const float4* src = (const float4*)(x + (size_t)b * TLEN * NCH + n0);
    #pragma unroll
    for (int t = tid; t < TLEN; t += TPB) {
        const float4 v = src[t * (NCH / 4)];
        lds[0 * RSTRIDE + t] = v.x;
        lds[1 * RSTRIDE + t] = v.y;
        lds[2 * RSTRIDE + t] = v.z;
        lds[3 * RSTRIDE + t] = v.w;
    }
    __syncthreads();

    dwt_level(lds, 0,       2048, CA1_OFF, CD1_OFF, tid);
    __syncthreads();
    dwt_level(lds, CA1_OFF, 1027, CA2_OFF, CD2_OFF, tid);
    __syncthreads();
    dwt_level(lds, CA2_OFF,  517, CA3_OFF, CD3_OFF, tid);
    __syncthreads();

    // ---- resize to 2048, write [row, t, 4] as NT float4 ----
    f32x4* dst = (f32x4*)out + (size_t)row0 * TLEN;
    #pragma unroll
    for (int t = tid; t < TLEN; t += TPB) {
        int i0a, i1a; float wa; lerp_coef( 262, t, i0a, i1a, wa);   // cA3 & cD3
        int i0b, i1b; float wb; lerp_coef( 517, t, i0b, i1b, wb);   // cD2
        int i0c, i1c; float wc; lerp_coef(1027, t, i0c, i1c, wc);   // cD1
        #pragma unroll
        for (int r = 0; r < ROWS; ++r) {
            const float* rowp = lds + r * RSTRIDE;
            f32x4 o;
            o.x = mix2(rowp[CA3_OFF + i0a], rowp[CA3_OFF + i1a], wa);
            o.y = mix2(rowp[CD3_OFF + i0a], rowp[CD3_OFF + i1a], wa);
            o.z = mix2(rowp[CD2_OFF + i0b], rowp[CD2_OFF + i1b], wb);
            o.w = mix2(rowp[CD1_OFF + i0c], rowp[CD1_OFF + i1c], wc);
            __builtin_nontemporal_store(o, &dst[r * TLEN + t]);
        }
    }
}

extern "C" void kernel_launch(void* const* d_in, const int* in_sizes, int n_in,
                              void* d_out, int out_size, void* d_ws, size_t ws_size,
                              hipStream_t stream) {
    const float* x = (const float*)d_in[0];
    float* out = (float*)d_out;
    const int n_rows = 16 * 512;                    // B*N
    dim3 grid(n_rows / ROWS), block(TPB);
    hipLaunchKernelGGL(dwt_kernel, grid, block, 0, stream, x, out);
}